// Round 5
// baseline (74.094 us; speedup 1.0000x reference)
//
#include <hip/hip_runtime.h>

// FieldWeightedFactorizationMachine forward — round 4: single-round-trip idx.
// B=32768 rows; F=39 fields; D=64 dims; V=1e6 vocab.
// One 64-lane wave per row: lane = dim d.
// - Row indices: ONE coalesced load (lane i -> idx_i), broadcast via __shfl
//   (no memory) -> all 39 NT gathers issue back-to-back after one round trip.
// - Embedding gathers non-temporal (skip L2: zero reuse, keeps bias resident).
// - Bias: lane i<39 contributes bias[idx_i]; folded into the shfl reduce.

#define FW_B 32768
#define FW_F 39
#define FW_D 64

__global__ __launch_bounds__(256) void fwfm_kernel(
    const int*   __restrict__ x,      // (B, F)
    const float* __restrict__ emb,    // (V, D)
    const float* __restrict__ bias,   // (V, 1)
    const float* __restrict__ W,      // (F, F)
    const float* __restrict__ w0,     // (1,)
    float*       __restrict__ out)    // (B,)
{
    const int wave = threadIdx.x >> 6;            // 0..3
    const int lane = threadIdx.x & 63;            // dim d
    const int row  = blockIdx.x * 4 + wave;
    if (row >= FW_B) return;

    // One coalesced load: lane i (i<39) holds idx_i; clamp tail lanes.
    const int xl   = (lane < FW_F) ? lane : (FW_F - 1);
    const int idxv = x[row * FW_F + xl];

    // Per-lane bias contribution (temporal load — want 4MB table L2-resident).
    float part = (lane < FW_F) ? bias[(unsigned)idxv] : 0.0f;

    // Broadcast idx_i to all lanes via shuffle (VALU, no memory round trip),
    // then issue all 39 non-temporal gathers back-to-back.
    float v[FW_F];
    #pragma unroll
    for (int i = 0; i < FW_F; ++i) {
        const int si = __shfl(idxv, i, 64);
        const unsigned off = (unsigned)si * (unsigned)FW_D + (unsigned)lane;
        v[i] = __builtin_nontemporal_load(emb + off);
    }

    // Upper-triangular weighted pairwise products for this lane's dim.
    // W reads are wave-uniform with compile-time offsets -> scalar loads.
    #pragma unroll
    for (int i = 0; i < FW_F - 1; ++i) {
        float s = 0.0f;
        #pragma unroll
        for (int j = i + 1; j < FW_F; ++j)
            s = fmaf(W[i * FW_F + j], v[j], s);
        part = fmaf(v[i], s, part);
    }

    // Reduce (interactions + bias) over the 64 lanes.
    #pragma unroll
    for (int off = 32; off >= 1; off >>= 1)
        part += __shfl_xor(part, off, 64);

    if (lane == 0)
        out[row] = w0[0] + part;
}

extern "C" void kernel_launch(void* const* d_in, const int* in_sizes, int n_in,
                              void* d_out, int out_size, void* d_ws, size_t ws_size,
                              hipStream_t stream) {
    const int*   x    = (const int*)  d_in[0];
    const float* emb  = (const float*)d_in[1];
    const float* bias = (const float*)d_in[2];
    const float* W    = (const float*)d_in[3];
    const float* w0   = (const float*)d_in[4];
    float* out        = (float*)d_out;

    const int rows_per_block = 4;                  // 4 waves x 64 lanes
    const int grid = (FW_B + rows_per_block - 1) / rows_per_block;
    fwfm_kernel<<<grid, 256, 0, stream>>>(x, emb, bias, W, w0, out);
}